// Round 2
// baseline (137.378 us; speedup 1.0000x reference)
//
#include <hip/hip_runtime.h>
#include <hip/hip_fp16.h>

// QLinear with per-k fp16 requantized accumulation (mptorch fma semantics).
// out = q16( q16_scan_fma( q8(x) @ q8(W)^T ) + q8(b) )
// v_pk_fma_f16 (single RNE) == reference fp32-mul/add/quant chain (fp32 add is
// exact for |acc|<64; double rounding 24b->11b is innocuous since 24>=2*11+2).
// R2: op_sel broadcasts x inside the FMA -> no LDS splatting; Tm=4 x Tn=8
// thread tile at 65536 threads (1 wave/SIMD) halves LDS read traffic.

#define M_DIM 2048
#define N_DIM 1024
#define K_DIM 1024

#define BM 64
#define BN 128
#define BK 64
// 256 threads: tn = t&15 (8 n each), tm = t>>4 (4 m each); grid 8 x 32 = 256 blocks

// dst.lo = x.lo*w.lo+acc.lo ; dst.hi = x.lo*w.hi+acc.hi
#define PKFMA_LO(acc, x, w) \
  asm("v_pk_fma_f16 %0, %1, %2, %0 op_sel:[0,0,0] op_sel_hi:[0,1,1]" \
      : "+v"(acc) : "v"(x), "v"(w))
// dst.lo = x.hi*w.lo+acc.lo ; dst.hi = x.hi*w.hi+acc.hi
#define PKFMA_HI(acc, x, w) \
  asm("v_pk_fma_f16 %0, %1, %2, %0 op_sel:[1,0,0] op_sel_hi:[1,1,1]" \
      : "+v"(acc) : "v"(x), "v"(w))

// exact E4M3 (exp=4, man=3) quantization of an fp32 value, result fp32
__device__ __forceinline__ float quant_e4m3(float v) {
  unsigned au = __float_as_uint(v) & 0x7fffffffu;
  if (au == 0u) return v;                 // +-0
  int e = (int)(au >> 23) - 127;          // floor(log2|v|) for normals
  if (e < -6) e = -6;                     // fp32 subnorms hit the clamp too
  float s  = __uint_as_float((unsigned)(130 - e) << 23);  // 2^(3-e), exact
  float is = __uint_as_float((unsigned)(124 + e) << 23);  // 2^(e-3), exact
  float r = rintf(v * s) * is;            // RNE (half-to-even), all steps exact
  return fminf(240.f, fmaxf(-240.f, r));
}

// Fused prep: blocks [0,2048) transpose-quant x, [2048,3072) transpose-quant w,
// block 3072 quantizes bias.
__global__ __launch_bounds__(256) void prep_kernel(const float* __restrict__ x,
                                                   const float* __restrict__ w,
                                                   const float* __restrict__ b,
                                                   __half* __restrict__ xT,
                                                   __half* __restrict__ wT,
                                                   float* __restrict__ qb) {
  const int id = blockIdx.x;
  if (id == 3072) {
    int i = threadIdx.x;
#pragma unroll
    for (int p = 0; p < 4; p++) qb[i + p * 256] = quant_e4m3(b[i + p * 256]);
    return;
  }
  const float* in;
  __half* outp;
  int R, C, bx, by;
  if (id < 2048) { in = x; outp = xT; R = M_DIM; C = K_DIM; bx = id & 31; by = id >> 5; }
  else           { in = w; outp = wT; R = N_DIM; C = K_DIM; bx = (id - 2048) & 31; by = (id - 2048) >> 5; }

  __shared__ float tile[32][33];
  const int tx = threadIdx.x & 31;
  const int ty = threadIdx.x >> 5;
  const int c0 = bx * 32;
  const int r0 = by * 32;
#pragma unroll
  for (int i = 0; i < 4; i++) {
    int r = r0 + ty + i * 8;
    tile[ty + i * 8][tx] = quant_e4m3(in[(size_t)r * C + c0 + tx]);
  }
  __syncthreads();
#pragma unroll
  for (int i = 0; i < 4; i++) {
    int c = c0 + ty + i * 8;
    outp[(size_t)c * R + r0 + tx] = __float2half(tile[tx][ty + i * 8]);
  }
}

// xT [K][M] fp16, wT [K][N] fp16, qb [N] fp32, out [M][N] fp32
__global__ __launch_bounds__(256) void gemm_qfma(const __half* __restrict__ xT,
                                                 const __half* __restrict__ wT,
                                                 const float* __restrict__ qb,
                                                 float* __restrict__ outp) {
  __shared__ __half xs[BK][BM];   //  8 KB, unsplatted
  __shared__ __half wsh[BK][BN];  // 16 KB, unsplatted

  const int tid = threadIdx.x;
  const int tn = tid & 15;   // 16 n-threads * 8 = BN
  const int tm = tid >> 4;   // 16 m-threads * 4 = BM
  const int bn0 = blockIdx.x * BN;
  const int bm0 = blockIdx.y * BM;

  unsigned acc[4][4];  // acc[i][j] = half2 {C(m_i, n_{2j}), C(m_i, n_{2j+1})}
#pragma unroll
  for (int i = 0; i < 4; i++)
#pragma unroll
    for (int j = 0; j < 4; j++) acc[i][j] = 0u;

  // staging indices (uint4 = 8 halfs per load)
  const int xr = tid >> 3, xc = (tid & 7) * 8;    // 2 passes of 32 rows
  const int wr = tid >> 4, wc = (tid & 15) * 8;   // 4 passes of 16 rows

  // register prefetch of chunk 0
  uint4 gx[2], gw[4];
#pragma unroll
  for (int p = 0; p < 2; p++)
    gx[p] = *reinterpret_cast<const uint4*>(xT + (size_t)(xr + p * 32) * M_DIM + bm0 + xc);
#pragma unroll
  for (int p = 0; p < 4; p++)
    gw[p] = *reinterpret_cast<const uint4*>(wT + (size_t)(wr + p * 16) * N_DIM + bn0 + wc);

  for (int kc = 0; kc < K_DIM; kc += BK) {
    __syncthreads();  // protect previous chunk's reads
#pragma unroll
    for (int p = 0; p < 2; p++)
      *reinterpret_cast<uint4*>(&xs[xr + p * 32][xc]) = gx[p];
#pragma unroll
    for (int p = 0; p < 4; p++)
      *reinterpret_cast<uint4*>(&wsh[wr + p * 16][wc]) = gw[p];
    __syncthreads();

    if (kc + BK < K_DIM) {  // prefetch next chunk during compute
      const int kn = kc + BK;
#pragma unroll
      for (int p = 0; p < 2; p++)
        gx[p] = *reinterpret_cast<const uint4*>(xT + (size_t)(kn + xr + p * 32) * M_DIM + bm0 + xc);
#pragma unroll
      for (int p = 0; p < 4; p++)
        gw[p] = *reinterpret_cast<const uint4*>(wT + (size_t)(kn + wr + p * 16) * N_DIM + bn0 + wc);
    }

#pragma unroll
    for (int kk = 0; kk < BK; kk++) {  // strictly ascending k (scan order via dep chain)
      const uint2 xv = *reinterpret_cast<const uint2*>(&xs[kk][tm * 4]);
      const uint4 wv = *reinterpret_cast<const uint4*>(&wsh[kk][tn * 8]);
      PKFMA_LO(acc[0][0], xv.x, wv.x); PKFMA_LO(acc[0][1], xv.x, wv.y);
      PKFMA_LO(acc[0][2], xv.x, wv.z); PKFMA_LO(acc[0][3], xv.x, wv.w);
      PKFMA_HI(acc[1][0], xv.x, wv.x); PKFMA_HI(acc[1][1], xv.x, wv.y);
      PKFMA_HI(acc[1][2], xv.x, wv.z); PKFMA_HI(acc[1][3], xv.x, wv.w);
      PKFMA_LO(acc[2][0], xv.y, wv.x); PKFMA_LO(acc[2][1], xv.y, wv.y);
      PKFMA_LO(acc[2][2], xv.y, wv.z); PKFMA_LO(acc[2][3], xv.y, wv.w);
      PKFMA_HI(acc[3][0], xv.y, wv.x); PKFMA_HI(acc[3][1], xv.y, wv.y);
      PKFMA_HI(acc[3][2], xv.y, wv.z); PKFMA_HI(acc[3][3], xv.y, wv.w);
    }
  }

  // epilogue: out = fp16RNE(acc + qb), stored fp32 (fp32 add exact here)
  const float4 bv0 = *reinterpret_cast<const float4*>(qb + bn0 + tn * 8);
  const float4 bv1 = *reinterpret_cast<const float4*>(qb + bn0 + tn * 8 + 4);
#pragma unroll
  for (int i = 0; i < 4; i++) {
    float4 o0, o1;
    __half2 h0 = *reinterpret_cast<__half2*>(&acc[i][0]);
    __half2 h1 = *reinterpret_cast<__half2*>(&acc[i][1]);
    __half2 h2 = *reinterpret_cast<__half2*>(&acc[i][2]);
    __half2 h3 = *reinterpret_cast<__half2*>(&acc[i][3]);
    o0.x = __half2float(__float2half(__low2float(h0)  + bv0.x));
    o0.y = __half2float(__float2half(__high2float(h0) + bv0.y));
    o0.z = __half2float(__float2half(__low2float(h1)  + bv0.z));
    o0.w = __half2float(__float2half(__high2float(h1) + bv0.w));
    o1.x = __half2float(__float2half(__low2float(h2)  + bv1.x));
    o1.y = __half2float(__float2half(__high2float(h2) + bv1.y));
    o1.z = __half2float(__float2half(__low2float(h3)  + bv1.z));
    o1.w = __half2float(__float2half(__high2float(h3) + bv1.w));
    float* row = outp + (size_t)(bm0 + tm * 4 + i) * N_DIM + bn0 + tn * 8;
    *reinterpret_cast<float4*>(row)     = o0;
    *reinterpret_cast<float4*>(row + 4) = o1;
  }
}

extern "C" void kernel_launch(void* const* d_in, const int* in_sizes, int n_in,
                              void* d_out, int out_size, void* d_ws, size_t ws_size,
                              hipStream_t stream) {
  const float* x = (const float*)d_in[0];   // [2048][1024]
  const float* w = (const float*)d_in[1];   // [1024][1024] (out_f, in_f)
  const float* b = (const float*)d_in[2];   // [1024]
  float* outp = (float*)d_out;              // [2048][1024] fp32

  char* ws = (char*)d_ws;
  __half* xT = (__half*)ws;                        // [K][M]  4 MiB
  __half* wT = (__half*)(ws + (size_t)(4 << 20));  // [K][N]  2 MiB
  float*  qb = (float*)(ws + (size_t)(6 << 20));   // [N]     4 KiB

  hipLaunchKernelGGL(prep_kernel, dim3(3073), dim3(256), 0, stream,
                     x, w, b, xT, wT, qb);
  hipLaunchKernelGGL(gemm_qfma, dim3(N_DIM / BN, M_DIM / BM), dim3(256), 0, stream,
                     xT, wT, qb, outp);
}

// Round 3
// 136.316 us; speedup vs baseline: 1.0078x; 1.0078x over previous
//
#include <hip/hip_runtime.h>
#include <hip/hip_fp16.h>

// QLinear with per-k fp16 requantized accumulation (mptorch fma semantics).
// out = q16( q16_scan_fma( q8(x) @ q8(W)^T ) + q8(b) )
// v_pk_fma_f16 (single RNE) == reference fp32-mul/add/quant chain (fp32 add is
// exact for |acc|<64; data max ~6).
// R3: R2 was latency-bound (1 wave/SIMD, VALUBusy 35%, VGPR=40 -> no compiler
// pipelining). Add ILP: double-buffered LDS (1 barrier/chunk, staging overlaps
// compute) + explicit 4-slot distance-3 register pipeline of inner ds_reads.

#define M_DIM 2048
#define N_DIM 1024
#define K_DIM 1024

#define BM 64
#define BN 128
#define BK 64
#define NCHUNK (K_DIM / BK)

// dst.lo = x.lo*w.lo+acc.lo ; dst.hi = x.lo*w.hi+acc.hi
#define PKFMA_LO(acc, x, w) \
  asm("v_pk_fma_f16 %0, %1, %2, %0 op_sel:[0,0,0] op_sel_hi:[0,1,1]" \
      : "+v"(acc) : "v"(x), "v"(w))
// dst.lo = x.hi*w.lo+acc.lo ; dst.hi = x.hi*w.hi+acc.hi
#define PKFMA_HI(acc, x, w) \
  asm("v_pk_fma_f16 %0, %1, %2, %0 op_sel:[1,0,0] op_sel_hi:[1,1,1]" \
      : "+v"(acc) : "v"(x), "v"(w))

// exact E4M3 (exp=4, man=3) quantization of an fp32 value, result fp32
__device__ __forceinline__ float quant_e4m3(float v) {
  unsigned au = __float_as_uint(v) & 0x7fffffffu;
  if (au == 0u) return v;                 // +-0
  int e = (int)(au >> 23) - 127;          // floor(log2|v|) for normals
  if (e < -6) e = -6;                     // fp32 subnorms hit the clamp too
  float s  = __uint_as_float((unsigned)(130 - e) << 23);  // 2^(3-e), exact
  float is = __uint_as_float((unsigned)(124 + e) << 23);  // 2^(e-3), exact
  float r = rintf(v * s) * is;            // RNE (half-to-even), all steps exact
  return fminf(240.f, fmaxf(-240.f, r));
}

// Fused prep: blocks [0,2048) transpose-quant x, [2048,3072) transpose-quant w,
// block 3072 quantizes bias.
__global__ __launch_bounds__(256) void prep_kernel(const float* __restrict__ x,
                                                   const float* __restrict__ w,
                                                   const float* __restrict__ b,
                                                   __half* __restrict__ xT,
                                                   __half* __restrict__ wT,
                                                   float* __restrict__ qb) {
  const int id = blockIdx.x;
  if (id == 3072) {
    int i = threadIdx.x;
#pragma unroll
    for (int p = 0; p < 4; p++) qb[i + p * 256] = quant_e4m3(b[i + p * 256]);
    return;
  }
  const float* in;
  __half* outp;
  int R, C, bx, by;
  if (id < 2048) { in = x; outp = xT; R = M_DIM; C = K_DIM; bx = id & 31; by = id >> 5; }
  else           { in = w; outp = wT; R = N_DIM; C = K_DIM; bx = (id - 2048) & 31; by = (id - 2048) >> 5; }

  __shared__ float tile[32][33];
  const int tx = threadIdx.x & 31;
  const int ty = threadIdx.x >> 5;
  const int c0 = bx * 32;
  const int r0 = by * 32;
#pragma unroll
  for (int i = 0; i < 4; i++) {
    int r = r0 + ty + i * 8;
    tile[ty + i * 8][tx] = quant_e4m3(in[(size_t)r * C + c0 + tx]);
  }
  __syncthreads();
#pragma unroll
  for (int i = 0; i < 4; i++) {
    int c = c0 + ty + i * 8;
    outp[(size_t)c * R + r0 + tx] = __float2half(tile[tx][ty + i * 8]);
  }
}

// xT [K][M] fp16, wT [K][N] fp16, qb [N] fp32, out [M][N] fp32
__global__ __launch_bounds__(256) void gemm_qfma(const __half* __restrict__ xT,
                                                 const __half* __restrict__ wT,
                                                 const float* __restrict__ qb,
                                                 float* __restrict__ outp) {
  __shared__ __half xs[2][BK][BM];   // 2 x  8 KB
  __shared__ __half wsh[2][BK][BN];  // 2 x 16 KB (48 KB total)

  const int tid = threadIdx.x;
  const int tn = tid & 15;   // 16 n-threads * 8 = BN
  const int tm = tid >> 4;   // 16 m-threads * 4 = BM
  const int tm4 = tm * 4, tn8 = tn * 8;
  const int bn0 = blockIdx.x * BN;
  const int bm0 = blockIdx.y * BM;

  unsigned acc[4][4];  // acc[i][j] = half2 {C(m_i, n_{2j}), C(m_i, n_{2j+1})}
#pragma unroll
  for (int i = 0; i < 4; i++)
#pragma unroll
    for (int j = 0; j < 4; j++) acc[i][j] = 0u;

  // staging indices (uint4 = 8 halfs per load)
  const int xr = tid >> 3, xc = (tid & 7) * 8;    // 2 passes of 32 rows
  const int wr = tid >> 4, wc = (tid & 15) * 8;   // 4 passes of 16 rows

  // global prefetch registers (chunk c+1 loaded during chunk c)
  uint4 gx[2], gw[4];
#pragma unroll
  for (int p = 0; p < 2; p++)
    gx[p] = *reinterpret_cast<const uint4*>(xT + (size_t)(xr + p * 32) * M_DIM + bm0 + xc);
#pragma unroll
  for (int p = 0; p < 4; p++)
    gw[p] = *reinterpret_cast<const uint4*>(wT + (size_t)(wr + p * 16) * N_DIM + bn0 + wc);

  for (int c = 0; c < NCHUNK; c++) {
    const int buf = c & 1;
    // stage chunk c into LDS buf (prev chunk's reads of this buf ended before
    // the barrier of chunk c-1, so no extra barrier needed here)
#pragma unroll
    for (int p = 0; p < 2; p++)
      *reinterpret_cast<uint4*>(&xs[buf][xr + p * 32][xc]) = gx[p];
#pragma unroll
    for (int p = 0; p < 4; p++)
      *reinterpret_cast<uint4*>(&wsh[buf][wr + p * 16][wc]) = gw[p];

    // global prefetch of chunk c+1 (completes while we compute chunk c)
    if (c + 1 < NCHUNK) {
      const int kn = (c + 1) * BK;
#pragma unroll
      for (int p = 0; p < 2; p++)
        gx[p] = *reinterpret_cast<const uint4*>(xT + (size_t)(kn + xr + p * 32) * M_DIM + bm0 + xc);
#pragma unroll
      for (int p = 0; p < 4; p++)
        gw[p] = *reinterpret_cast<const uint4*>(wT + (size_t)(kn + wr + p * 16) * N_DIM + bn0 + wc);
    }

    __syncthreads();

    const __half (*xsb)[BM] = xs[buf];
    const __half (*wsb)[BN] = wsh[buf];

    // software-pipelined inner loop: 4 slots, prefetch distance 3
    uint2 xv[4];
    uint4 wv[4];
#pragma unroll
    for (int s = 0; s < 3; s++) {
      xv[s] = *reinterpret_cast<const uint2*>(&xsb[s][tm4]);
      wv[s] = *reinterpret_cast<const uint4*>(&wsb[s][tn8]);
    }
#pragma unroll
    for (int kk = 0; kk < BK; kk++) {   // strictly ascending k (scan order)
      const int s = kk & 3;
      if (kk + 3 < BK) {
        const int sp = (kk + 3) & 3;
        xv[sp] = *reinterpret_cast<const uint2*>(&xsb[kk + 3][tm4]);
        wv[sp] = *reinterpret_cast<const uint4*>(&wsb[kk + 3][tn8]);
      }
      const unsigned x0 = xv[s].x, x1 = xv[s].y;
      const uint4 wq = wv[s];
      PKFMA_LO(acc[0][0], x0, wq.x); PKFMA_LO(acc[0][1], x0, wq.y);
      PKFMA_LO(acc[0][2], x0, wq.z); PKFMA_LO(acc[0][3], x0, wq.w);
      PKFMA_HI(acc[1][0], x0, wq.x); PKFMA_HI(acc[1][1], x0, wq.y);
      PKFMA_HI(acc[1][2], x0, wq.z); PKFMA_HI(acc[1][3], x0, wq.w);
      PKFMA_LO(acc[2][0], x1, wq.x); PKFMA_LO(acc[2][1], x1, wq.y);
      PKFMA_LO(acc[2][2], x1, wq.z); PKFMA_LO(acc[2][3], x1, wq.w);
      PKFMA_HI(acc[3][0], x1, wq.x); PKFMA_HI(acc[3][1], x1, wq.y);
      PKFMA_HI(acc[3][2], x1, wq.z); PKFMA_HI(acc[3][3], x1, wq.w);
    }
    __syncthreads();  // all reads of buf done before it is overwritten (c+2)
  }

  // epilogue: out = fp16RNE(acc + qb), stored fp32 (fp32 add exact here)
  const float4 bv0 = *reinterpret_cast<const float4*>(qb + bn0 + tn8);
  const float4 bv1 = *reinterpret_cast<const float4*>(qb + bn0 + tn8 + 4);
#pragma unroll
  for (int i = 0; i < 4; i++) {
    float4 o0, o1;
    __half2 h0 = *reinterpret_cast<__half2*>(&acc[i][0]);
    __half2 h1 = *reinterpret_cast<__half2*>(&acc[i][1]);
    __half2 h2 = *reinterpret_cast<__half2*>(&acc[i][2]);
    __half2 h3 = *reinterpret_cast<__half2*>(&acc[i][3]);
    o0.x = __half2float(__float2half(__low2float(h0)  + bv0.x));
    o0.y = __half2float(__float2half(__high2float(h0) + bv0.y));
    o0.z = __half2float(__float2half(__low2float(h1)  + bv0.z));
    o0.w = __half2float(__float2half(__high2float(h1) + bv0.w));
    o1.x = __half2float(__float2half(__low2float(h2)  + bv1.x));
    o1.y = __half2float(__float2half(__high2float(h2) + bv1.y));
    o1.z = __half2float(__float2half(__low2float(h3)  + bv1.z));
    o1.w = __half2float(__float2half(__high2float(h3) + bv1.w));
    float* row = outp + (size_t)(bm0 + tm4 + i) * N_DIM + bn0 + tn8;
    *reinterpret_cast<float4*>(row)     = o0;
    *reinterpret_cast<float4*>(row + 4) = o1;
  }
}

extern "C" void kernel_launch(void* const* d_in, const int* in_sizes, int n_in,
                              void* d_out, int out_size, void* d_ws, size_t ws_size,
                              hipStream_t stream) {
  const float* x = (const float*)d_in[0];   // [2048][1024]
  const float* w = (const float*)d_in[1];   // [1024][1024] (out_f, in_f)
  const float* b = (const float*)d_in[2];   // [1024]
  float* outp = (float*)d_out;              // [2048][1024] fp32

  char* ws = (char*)d_ws;
  __half* xT = (__half*)ws;                        // [K][M]  4 MiB
  __half* wT = (__half*)(ws + (size_t)(4 << 20));  // [K][N]  2 MiB
  float*  qb = (float*)(ws + (size_t)(6 << 20));   // [N]     4 KiB

  hipLaunchKernelGGL(prep_kernel, dim3(3073), dim3(256), 0, stream,
                     x, w, b, xT, wT, qb);
  hipLaunchKernelGGL(gemm_qfma, dim3(N_DIM / BN, M_DIM / BM), dim3(256), 0, stream,
                     xT, wT, qb, outp);
}

// Round 4
// 123.891 us; speedup vs baseline: 1.1089x; 1.1003x over previous
//
#include <hip/hip_runtime.h>
#include <hip/hip_fp16.h>

// QLinear with per-k fp16 requantized accumulation (mptorch fma semantics).
// out = q16( q16_scan_fma( q8(x) @ q8(W)^T ) + q8(b) )
// v_pk_fma_f16 (single RNE) == reference fp32-mul/add/quant chain (fp32 add is
// exact for |acc|<64; data max ~6).
// R4: R1 calibration shows 8 waves/CU fully hides ds_read latency and runs at
// the LDS read-issue ceiling; R2/R3's 4 waves/CU (1/SIMD) was latency-bound.
// -> 64x64 tiles, 512 blocks (8 waves/CU, 2 independent blocks/CU) with
// unsplatted op_sel reads: 2x ds_read_b64 = 16 B/thread/k (R1 was 24).

#define M_DIM 2048
#define N_DIM 1024
#define K_DIM 1024

#define BM 64
#define BN 64
#define BK 64
#define NCHUNK (K_DIM / BK)

// dst.lo = x.lo*w.lo+acc.lo ; dst.hi = x.lo*w.hi+acc.hi
#define PKFMA_LO(acc, x, w) \
  asm("v_pk_fma_f16 %0, %1, %2, %0 op_sel:[0,0,0] op_sel_hi:[0,1,1]" \
      : "+v"(acc) : "v"(x), "v"(w))
// dst.lo = x.hi*w.lo+acc.lo ; dst.hi = x.hi*w.hi+acc.hi
#define PKFMA_HI(acc, x, w) \
  asm("v_pk_fma_f16 %0, %1, %2, %0 op_sel:[1,0,0] op_sel_hi:[1,1,1]" \
      : "+v"(acc) : "v"(x), "v"(w))

// exact E4M3 (exp=4, man=3) quantization of an fp32 value, result fp32
__device__ __forceinline__ float quant_e4m3(float v) {
  unsigned au = __float_as_uint(v) & 0x7fffffffu;
  if (au == 0u) return v;                 // +-0
  int e = (int)(au >> 23) - 127;          // floor(log2|v|) for normals
  if (e < -6) e = -6;                     // fp32 subnorms hit the clamp too
  float s  = __uint_as_float((unsigned)(130 - e) << 23);  // 2^(3-e), exact
  float is = __uint_as_float((unsigned)(124 + e) << 23);  // 2^(e-3), exact
  float r = rintf(v * s) * is;            // RNE (half-to-even), all steps exact
  return fminf(240.f, fmaxf(-240.f, r));
}

// Fused prep: blocks [0,2048) transpose-quant x, [2048,3072) transpose-quant w.
__global__ __launch_bounds__(256) void prep_kernel(const float* __restrict__ x,
                                                   const float* __restrict__ w,
                                                   __half* __restrict__ xT,
                                                   __half* __restrict__ wT) {
  const int id = blockIdx.x;
  const float* in;
  __half* outp;
  int R, C, bx, by;
  if (id < 2048) { in = x; outp = xT; R = M_DIM; C = K_DIM; bx = id & 31; by = id >> 5; }
  else           { in = w; outp = wT; R = N_DIM; C = K_DIM; bx = (id - 2048) & 31; by = (id - 2048) >> 5; }

  __shared__ float tile[32][33];
  const int tx = threadIdx.x & 31;
  const int ty = threadIdx.x >> 5;
  const int c0 = bx * 32;
  const int r0 = by * 32;
#pragma unroll
  for (int i = 0; i < 4; i++) {
    int r = r0 + ty + i * 8;
    tile[ty + i * 8][tx] = quant_e4m3(in[(size_t)r * C + c0 + tx]);
  }
  __syncthreads();
#pragma unroll
  for (int i = 0; i < 4; i++) {
    int c = c0 + ty + i * 8;
    outp[(size_t)c * R + r0 + tx] = __float2half(tile[tx][ty + i * 8]);
  }
}

// xT [K][M] fp16, wT [K][N] fp16, b [N] fp32 (raw), out [M][N] fp32
__global__ __launch_bounds__(256) void gemm_qfma(const __half* __restrict__ xT,
                                                 const __half* __restrict__ wT,
                                                 const float* __restrict__ b,
                                                 float* __restrict__ outp) {
  __shared__ __half xs[2][BK][BM];   // 2 x 8 KB
  __shared__ __half wsh[2][BK][BN];  // 2 x 8 KB (32 KB total -> 2 blocks/CU ok)

  const int tid = threadIdx.x;
  const int tn = tid & 15;   // 16 n-threads * 4 = BN
  const int tm = tid >> 4;   // 16 m-threads * 4 = BM
  const int tm4 = tm * 4, tn4 = tn * 4;
  const int bn0 = blockIdx.x * BN;
  const int bm0 = blockIdx.y * BM;

  unsigned acc[4][2];  // acc[i][j] = half2 {C(m_i, n_{2j}), C(m_i, n_{2j+1})}
#pragma unroll
  for (int i = 0; i < 4; i++)
#pragma unroll
    for (int j = 0; j < 2; j++) acc[i][j] = 0u;

  // staging: 8 threads x 8 halfs cover 64 cols; 32 rows per pass, 2 passes
  const int sr = tid >> 3, sc = (tid & 7) * 8;

  // global prefetch registers (chunk c+1 loaded during chunk c)
  uint4 gx[2], gw[2];
#pragma unroll
  for (int p = 0; p < 2; p++) {
    gx[p] = *reinterpret_cast<const uint4*>(xT + (size_t)(sr + p * 32) * M_DIM + bm0 + sc);
    gw[p] = *reinterpret_cast<const uint4*>(wT + (size_t)(sr + p * 32) * N_DIM + bn0 + sc);
  }

  for (int c = 0; c < NCHUNK; c++) {
    const int buf = c & 1;
#pragma unroll
    for (int p = 0; p < 2; p++) {
      *reinterpret_cast<uint4*>(&xs[buf][sr + p * 32][sc]) = gx[p];
      *reinterpret_cast<uint4*>(&wsh[buf][sr + p * 32][sc]) = gw[p];
    }

    if (c + 1 < NCHUNK) {  // prefetch next chunk during compute
      const int kn = (c + 1) * BK;
#pragma unroll
      for (int p = 0; p < 2; p++) {
        gx[p] = *reinterpret_cast<const uint4*>(xT + (size_t)(kn + sr + p * 32) * M_DIM + bm0 + sc);
        gw[p] = *reinterpret_cast<const uint4*>(wT + (size_t)(kn + sr + p * 32) * N_DIM + bn0 + sc);
      }
    }

    __syncthreads();

    const __half (*xsb)[BM] = xs[buf];
    const __half (*wsb)[BN] = wsh[buf];

    // software-pipelined inner loop: 4 slots, prefetch distance 3
    uint2 xv[4], wv[4];
#pragma unroll
    for (int s = 0; s < 3; s++) {
      xv[s] = *reinterpret_cast<const uint2*>(&xsb[s][tm4]);
      wv[s] = *reinterpret_cast<const uint2*>(&wsb[s][tn4]);
    }
#pragma unroll
    for (int kk = 0; kk < BK; kk++) {   // strictly ascending k (scan order)
      const int s = kk & 3;
      if (kk + 3 < BK) {
        const int sp = (kk + 3) & 3;
        xv[sp] = *reinterpret_cast<const uint2*>(&xsb[kk + 3][tm4]);
        wv[sp] = *reinterpret_cast<const uint2*>(&wsb[kk + 3][tn4]);
      }
      const unsigned x0 = xv[s].x, x1 = xv[s].y;
      const unsigned w0 = wv[s].x, w1 = wv[s].y;
      PKFMA_LO(acc[0][0], x0, w0); PKFMA_LO(acc[0][1], x0, w1);
      PKFMA_HI(acc[1][0], x0, w0); PKFMA_HI(acc[1][1], x0, w1);
      PKFMA_LO(acc[2][0], x1, w0); PKFMA_LO(acc[2][1], x1, w1);
      PKFMA_HI(acc[3][0], x1, w0); PKFMA_HI(acc[3][1], x1, w1);
    }
    __syncthreads();  // all reads of buf done before it is overwritten (c+2)
  }

  // epilogue: out = fp16RNE(acc + q8(b)), stored fp32 (fp32 add exact here)
  float4 bq = *reinterpret_cast<const float4*>(b + bn0 + tn4);
  bq.x = quant_e4m3(bq.x); bq.y = quant_e4m3(bq.y);
  bq.z = quant_e4m3(bq.z); bq.w = quant_e4m3(bq.w);
#pragma unroll
  for (int i = 0; i < 4; i++) {
    float4 o;
    __half2 h0 = *reinterpret_cast<__half2*>(&acc[i][0]);
    __half2 h1 = *reinterpret_cast<__half2*>(&acc[i][1]);
    o.x = __half2float(__float2half(__low2float(h0)  + bq.x));
    o.y = __half2float(__float2half(__high2float(h0) + bq.y));
    o.z = __half2float(__float2half(__low2float(h1)  + bq.z));
    o.w = __half2float(__float2half(__high2float(h1) + bq.w));
    *reinterpret_cast<float4*>(outp + (size_t)(bm0 + tm4 + i) * N_DIM + bn0 + tn4) = o;
  }
}

extern "C" void kernel_launch(void* const* d_in, const int* in_sizes, int n_in,
                              void* d_out, int out_size, void* d_ws, size_t ws_size,
                              hipStream_t stream) {
  const float* x = (const float*)d_in[0];   // [2048][1024]
  const float* w = (const float*)d_in[1];   // [1024][1024] (out_f, in_f)
  const float* b = (const float*)d_in[2];   // [1024]
  float* outp = (float*)d_out;              // [2048][1024] fp32

  char* ws = (char*)d_ws;
  __half* xT = (__half*)ws;                        // [K][M]  4 MiB
  __half* wT = (__half*)(ws + (size_t)(4 << 20));  // [K][N]  2 MiB

  hipLaunchKernelGGL(prep_kernel, dim3(3072), dim3(256), 0, stream,
                     x, w, xT, wT);
  hipLaunchKernelGGL(gemm_qfma, dim3(N_DIM / BN, M_DIM / BM), dim3(256), 0, stream,
                     xT, wT, b, outp);
}